// Round 13
// baseline (289.072 us; speedup 1.0000x reference)
//
#include <hip/hip_runtime.h>
#include <hip/hip_fp16.h>
#include <math.h>

// Problem constants: B=2, K=128, L=4096, DK=DL=128, HID=128
constexpr int BB = 2;
constexpr int KK = 128;
constexpr int LL = 4096;
constexpr int DD = 128;
constexpr int HH = 128;
constexpr int REP = 16;     // PROBE: idempotent body repeat so kernels rank
                            // above the ~40us harness fills in rocprof top-5

__device__ __forceinline__ float4 ld4(const float* p) {
    return *reinterpret_cast<const float4*>(p);
}

// packed fp16 max — emits v_pk_max_f16
__device__ __forceinline__ __half2 hmax2(__half2 a, __half2 b) {
    unsigned ua = __builtin_bit_cast(unsigned, a);
    unsigned ub = __builtin_bit_cast(unsigned, b);
    unsigned ud;
    asm("v_pk_max_f16 %0, %1, %2" : "=v"(ud) : "v"(ua), "v"(ub));
    return __builtin_bit_cast(__half2, ud);
}

// duplicate fp16(x) into both halves of a dword
__device__ __forceinline__ uint32_t duph(float x) {
    __half h = __float2half(x);
    unsigned short us = __builtin_bit_cast(unsigned short, h);
    return (uint32_t)us * 0x10001u;
}

// ---------------------------------------------------------------------------
// K1 (R12 body, x REP): 264 blocks x 256 threads, 32 virtual rows each.
// ---------------------------------------------------------------------------
__global__ __launch_bounds__(256) void k1_gemm(
    const float* __restrict__ inA, const float* __restrict__ inB,
    const float* __restrict__ W1, const float* __restrict__ b1,
    const float* __restrict__ w2,
    uint32_t* __restrict__ u_dup, uint32_t* __restrict__ w2_dup,
    __half* __restrict__ vT)
{
    __shared__ __align__(16) char smem[49 * 1024];
    float*  sIn = reinterpret_cast<float*>(smem);               // 16 KiB
    float4* sW4 = reinterpret_cast<float4*>(smem + 16 * 1024);  // 32 KiB
    float*  sT  = reinterpret_cast<float*>(smem + 16 * 1024);   // 17 KiB overlay

    const int bid = blockIdx.x;
    const int tid = threadIdx.x;

    int row0;
    bool isA;
    if (bid < 256) {
        const int x = bid & 7, y = bid >> 3;
        const int C = x + 8 * (y & 1);
        row0 = C * 512 + (y >> 1) * 32;    // B virtual row (b*4096 + l)
        isA = false;
    } else {
        row0 = (bid - 256) * 32;           // u row
        isA = true;
    }
    const float* src = (isA ? inA : inB) + (size_t)row0 * DD;
    const float4* wsrc = reinterpret_cast<const float4*>(W1 + (isA ? 0 : DD * HH));

    for (int rep = 0; rep < REP; ++rep) {
      __syncthreads();
      #pragma unroll
      for (int j = 0; j < 4; ++j) {
          const int idx = tid + 256 * j;
          reinterpret_cast<float4*>(sIn)[idx] =
              reinterpret_cast<const float4*>(src)[idx];
      }

      const int tx = tid & 31;
      const int ty = tid >> 5;

      float accx[4], accy[4], accz[4], accw[4];
      #pragma unroll
      for (int r = 0; r < 4; ++r) { accx[r] = accy[r] = accz[r] = accw[r] = 0.f; }

      for (int wh = 0; wh < 2; ++wh) {
          __syncthreads();
          #pragma unroll
          for (int q = 0; q < 8; ++q)
              sW4[tid + 256 * q] = wsrc[wh * 2048 + tid + 256 * q];
          __syncthreads();

          #pragma unroll 2
          for (int dd0 = 0; dd0 < 64; dd0 += 4) {
              const int d0 = wh * 64 + dd0;
              float4 w4[4];
              #pragma unroll
              for (int dd = 0; dd < 4; ++dd)
                  w4[dd] = sW4[(dd0 + dd) * 32 + tx];
              float a[4][4];
              #pragma unroll
              for (int r = 0; r < 4; ++r) {
                  float4 a4 = ld4(&sIn[(ty * 4 + r) * 128 + d0]);
                  a[r][0] = a4.x; a[r][1] = a4.y; a[r][2] = a4.z; a[r][3] = a4.w;
              }
              #pragma unroll
              for (int dd = 0; dd < 4; ++dd) {
                  const float4 wv = w4[dd];
                  #pragma unroll
                  for (int r = 0; r < 4; ++r) {
                      const float av = a[r][dd];
                      accx[r] = fmaf(av, wv.x, accx[r]);
                      accy[r] = fmaf(av, wv.y, accy[r]);
                      accz[r] = fmaf(av, wv.z, accz[r]);
                      accw[r] = fmaf(av, wv.w, accw[r]);
                  }
              }
          }
      }

      if (isA) {
          const float4 bb = ld4(&b1[tx * 4]);
          #pragma unroll
          for (int r = 0; r < 4; ++r) {
              uint4 o;
              o.x = duph(accx[r] + bb.x);
              o.y = duph(accy[r] + bb.y);
              o.z = duph(accz[r] + bb.z);
              o.w = duph(accw[r] + bb.w);
              *reinterpret_cast<uint4*>(
                  &u_dup[(size_t)(row0 + ty * 4 + r) * HH + tx * 4]) = o;
          }
          if (bid == 256 && tid < HH) w2_dup[tid] = duph(w2[tid]);
          __syncthreads();
      } else {
          __syncthreads();
          #pragma unroll
          for (int r = 0; r < 4; ++r) {
              const int l = ty * 4 + r;
              sT[(tx * 4 + 0) * 33 + l] = accx[r];
              sT[(tx * 4 + 1) * 33 + l] = accy[r];
              sT[(tx * 4 + 2) * 33 + l] = accz[r];
              sT[(tx * 4 + 3) * 33 + l] = accw[r];
          }
          __syncthreads();
          const int h    = tid >> 1;
          const int half = tid & 1;
          const int bsel = row0 >> 12;
          const int l0   = (row0 & 4095) + half * 16;
          uint32_t o[8];
          #pragma unroll
          for (int i = 0; i < 8; ++i) {
              const float lo = sT[h * 33 + half * 16 + 2 * i];
              const float hi = sT[h * 33 + half * 16 + 2 * i + 1];
              o[i] = __builtin_bit_cast(uint32_t, __floats2half2_rn(lo, hi));
          }
          uint32_t* dst = reinterpret_cast<uint32_t*>(vT) +
                          (size_t)(bsel * HH + h) * (LL / 2) + l0 / 2;
          uint4 s0; s0.x = o[0]; s0.y = o[1]; s0.z = o[2]; s0.w = o[3];
          uint4 s1; s1.x = o[4]; s1.y = o[5]; s1.z = o[6]; s1.w = o[7];
          *reinterpret_cast<uint4*>(dst)     = s0;
          *reinterpret_cast<uint4*>(dst + 4) = s1;
      }
    }
}

// ---------------------------------------------------------------------------
// K2 (R12 body, x REP): 256 blocks x 512 threads, writes raw scores to ws.
// ---------------------------------------------------------------------------
__global__ __launch_bounds__(512) void k2_score(
    const uint32_t* __restrict__ u_dup, const uint32_t* __restrict__ w2_dup,
    const __half* __restrict__ vT, float* __restrict__ scores)
{
    __shared__ __align__(16) uint32_t sU[8 * HH];   // 4 KiB
    __shared__ __align__(16) uint32_t sW[HH];       // 512 B

    int m = blockIdx.x;
    const int cb = m & 7;   m >>= 3;
    const int kt = m & 15;  m >>= 4;
    const int b  = m;
    const int tid = threadIdx.x;

    for (int rep = 0; rep < REP; ++rep) {
      __syncthreads();
      if (tid < 256)
          reinterpret_cast<uint4*>(sU)[tid] =
              reinterpret_cast<const uint4*>(u_dup + (size_t)(b * KK + kt * 8) * HH)[tid];
      else if (tid < 288)
          reinterpret_cast<uint4*>(sW)[tid - 256] =
              reinterpret_cast<const uint4*>(w2_dup)[tid - 256];
      __syncthreads();

      const int kh = tid >> 8;
      const int t  = tid & 255;
      const int p  = cb * 256 + t;
      const uint32_t* vp = reinterpret_cast<const uint32_t*>(vT)
                           + (size_t)b * HH * (LL / 2) + p;
      const uint32_t* su = sU + kh * 4 * HH;

      const __half2 hz = __float2half2_rn(0.f);
      float2 facc[4];
      #pragma unroll
      for (int k = 0; k < 4; ++k) { facc[k].x = 0.f; facc[k].y = 0.f; }

      for (int g = 0; g < 8; ++g) {
          const int h0 = g * 16;
          uint32_t v[16];
          #pragma unroll
          for (int jj = 0; jj < 16; ++jj)
              v[jj] = vp[(size_t)(h0 + jj) * (LL / 2)];

          __half2 acc[4];
          #pragma unroll
          for (int k = 0; k < 4; ++k) acc[k] = hz;

          #pragma unroll
          for (int q = 0; q < 4; ++q) {
              const uint4 wc = *reinterpret_cast<const uint4*>(&sW[h0 + q * 4]);
              uint4 uc[4];
              #pragma unroll
              for (int k = 0; k < 4; ++k)
                  uc[k] = *reinterpret_cast<const uint4*>(&su[k * HH + h0 + q * 4]);
              const uint32_t* wq = reinterpret_cast<const uint32_t*>(&wc);
              #pragma unroll
              for (int jj = 0; jj < 4; ++jj) {
                  const __half2 ww = __builtin_bit_cast(__half2, wq[jj]);
                  const __half2 vv = __builtin_bit_cast(__half2, v[q * 4 + jj]);
                  #pragma unroll
                  for (int k = 0; k < 4; ++k) {
                      const uint32_t* uq = reinterpret_cast<const uint32_t*>(&uc[k]);
                      __half2 tt = __hadd2(vv, __builtin_bit_cast(__half2, uq[jj]));
                      acc[k] = __hfma2(hmax2(tt, hz), ww, acc[k]);
                  }
              }
          }
          #pragma unroll
          for (int k = 0; k < 4; ++k) {
              const float2 f = __half22float2(acc[k]);
              facc[k].x += f.x; facc[k].y += f.y;
          }
      }

      #pragma unroll
      for (int k = 0; k < 4; ++k)
          *reinterpret_cast<float2*>(
              &scores[(size_t)(b * KK + kt * 8 + kh * 4 + k) * LL + 2 * p]) = facc[k];
    }
}

// ---------------------------------------------------------------------------
// K3 (x REP): max-free row softmax, scores (ws) -> d_out. NOT in-place so the
// repeat is idempotent. 256 blocks x 1024 threads.
// ---------------------------------------------------------------------------
__global__ __launch_bounds__(1024) void k3_softmax(
    const float* __restrict__ scores, float* __restrict__ out)
{
    __shared__ float reds[16];

    const int row = blockIdx.x;
    const float* ps = scores + (size_t)row * LL;
    float* po = out + (size_t)row * LL;
    const int tid = threadIdx.x;

    for (int rep = 0; rep < REP; ++rep) {
      __syncthreads();
      float4 x = reinterpret_cast<const float4*>(ps)[tid];

      x.x = expf(x.x); x.y = expf(x.y);
      x.z = expf(x.z); x.w = expf(x.w);
      float s = (x.x + x.y) + (x.z + x.w);
      #pragma unroll
      for (int off = 32; off > 0; off >>= 1)
          s += __shfl_xor(s, off, 64);
      const int lane = tid & 63, wv = tid >> 6;
      if (lane == 0) reds[wv] = s;
      __syncthreads();
      if (tid < 16) {
          float ss = reds[tid];
          #pragma unroll
          for (int off = 8; off > 0; off >>= 1)
              ss += __shfl_xor(ss, off, 64);
          reds[tid] = ss;
      }
      __syncthreads();
      s = reds[0];

      const float inv = 1.0f / s;
      x.x *= inv; x.y *= inv; x.z *= inv; x.w *= inv;
      reinterpret_cast<float4*>(po)[tid] = x;
    }
}

// ---------------------------------------------------------------------------
extern "C" void kernel_launch(void* const* d_in, const int* in_sizes, int n_in,
                              void* d_out, int out_size, void* d_ws, size_t ws_size,
                              hipStream_t stream)
{
    const float* inA = (const float*)d_in[0];
    const float* inB = (const float*)d_in[1];
    const float* W1  = (const float*)d_in[2];
    const float* b1  = (const float*)d_in[3];
    const float* w2  = (const float*)d_in[4];
    float* out = (float*)d_out;

    char* ws = (char*)d_ws;
    uint32_t* u_dup  = (uint32_t*)ws;                      // 128 KiB
    uint32_t* w2_dup = (uint32_t*)(ws + 0x20000);          // 512 B
    __half*   vT     = (__half*)(ws + 0x40000);            // 2 MiB
    float*    scores = (float*)(ws + 0x280000);            // 4 MiB

    hipLaunchKernelGGL(k1_gemm, dim3(264), dim3(256), 0, stream,
                       inA, inB, W1, b1, w2, u_dup, w2_dup, vT);
    hipLaunchKernelGGL(k2_score, dim3(256), dim3(512), 0, stream,
                       u_dup, w2_dup, vT, scores);
    hipLaunchKernelGGL(k3_softmax, dim3(BB * KK), dim3(1024), 0, stream,
                       scores, out);
}

// Round 14
// 31.395 us; speedup vs baseline: 9.2076x; 9.2076x over previous
//
#include <hip/hip_runtime.h>
#include <hip/hip_fp16.h>
#include <math.h>

// Problem constants: B=2, K=128, L=4096, DK=DL=128, HID=128
constexpr int BB = 2;
constexpr int KK = 128;
constexpr int LL = 4096;
constexpr int DD = 128;
constexpr int HH = 128;

__device__ __forceinline__ float4 ld4(const float* p) {
    return *reinterpret_cast<const float4*>(p);
}

// packed fp16 max — emits v_pk_max_f16
__device__ __forceinline__ __half2 hmax2(__half2 a, __half2 b) {
    unsigned ua = __builtin_bit_cast(unsigned, a);
    unsigned ub = __builtin_bit_cast(unsigned, b);
    unsigned ud;
    asm("v_pk_max_f16 %0, %1, %2" : "=v"(ud) : "v"(ua), "v"(ub));
    return __builtin_bit_cast(__half2, ud);
}

// pack two floats into a half2 dword
__device__ __forceinline__ uint32_t pkh2(float a, float b) {
    return __builtin_bit_cast(uint32_t, __floats2half2_rn(a, b));
}

// ---------------------------------------------------------------------------
// K1: 264 blocks x 256 threads, 32 virtual rows each. W1-half staged into LDS
// in two 32 KB chunks (R10-proven). NO transpose: B-rows stored as natural
// row-major fp16 v[l][h]; A-rows as u_pk[k][hp] (h0,h1) fp16 pairs; block 256
// packs w2_pk. B-tiles XCD-swizzled: writer XCD = (l-chunk)&7 = k2 reader.
// ---------------------------------------------------------------------------
__global__ __launch_bounds__(256) void k1_gemm(
    const float* __restrict__ inA, const float* __restrict__ inB,
    const float* __restrict__ W1, const float* __restrict__ b1,
    const float* __restrict__ w2,
    uint32_t* __restrict__ u_pk, uint32_t* __restrict__ w2_pk,
    __half* __restrict__ vh)
{
    __shared__ __align__(16) char smem[48 * 1024];
    float*  sIn = reinterpret_cast<float*>(smem);               // 16 KiB
    float4* sW4 = reinterpret_cast<float4*>(smem + 16 * 1024);  // 32 KiB

    const int bid = blockIdx.x;
    const int tid = threadIdx.x;

    int row0;
    bool isA;
    if (bid < 256) {
        const int x = bid & 7, y = bid >> 3;
        const int C = x + 8 * (y & 1);
        row0 = C * 512 + (y >> 1) * 32;    // B virtual row (b*4096 + l)
        isA = false;
    } else {
        row0 = (bid - 256) * 32;           // u row
        isA = true;
    }
    const float* src = (isA ? inA : inB) + (size_t)row0 * DD;
    const float4* wsrc = reinterpret_cast<const float4*>(W1 + (isA ? 0 : DD * HH));

    #pragma unroll
    for (int j = 0; j < 4; ++j) {
        const int idx = tid + 256 * j;
        reinterpret_cast<float4*>(sIn)[idx] =
            reinterpret_cast<const float4*>(src)[idx];
    }

    const int tx = tid & 31;   // h-cols tx*4 .. tx*4+3
    const int ty = tid >> 5;   // rows ty*4 .. ty*4+3

    float accx[4], accy[4], accz[4], accw[4];
    #pragma unroll
    for (int r = 0; r < 4; ++r) { accx[r] = accy[r] = accz[r] = accw[r] = 0.f; }

    for (int wh = 0; wh < 2; ++wh) {
        __syncthreads();
        #pragma unroll
        for (int q = 0; q < 8; ++q)
            sW4[tid + 256 * q] = wsrc[wh * 2048 + tid + 256 * q];
        __syncthreads();

        #pragma unroll 2
        for (int dd0 = 0; dd0 < 64; dd0 += 4) {
            const int d0 = wh * 64 + dd0;
            float4 w4[4];
            #pragma unroll
            for (int dd = 0; dd < 4; ++dd)
                w4[dd] = sW4[(dd0 + dd) * 32 + tx];
            float a[4][4];
            #pragma unroll
            for (int r = 0; r < 4; ++r) {
                float4 a4 = ld4(&sIn[(ty * 4 + r) * 128 + d0]);
                a[r][0] = a4.x; a[r][1] = a4.y; a[r][2] = a4.z; a[r][3] = a4.w;
            }
            #pragma unroll
            for (int dd = 0; dd < 4; ++dd) {
                const float4 wv = w4[dd];
                #pragma unroll
                for (int r = 0; r < 4; ++r) {
                    const float av = a[r][dd];
                    accx[r] = fmaf(av, wv.x, accx[r]);
                    accy[r] = fmaf(av, wv.y, accy[r]);
                    accz[r] = fmaf(av, wv.z, accz[r]);
                    accw[r] = fmaf(av, wv.w, accw[r]);
                }
            }
        }
    }

    if (isA) {
        const float4 bb = ld4(&b1[tx * 4]);
        #pragma unroll
        for (int r = 0; r < 4; ++r) {
            uint2 o;
            o.x = pkh2(accx[r] + bb.x, accy[r] + bb.y);
            o.y = pkh2(accz[r] + bb.z, accw[r] + bb.w);
            // u_pk row = 64 dwords; cols tx*4..tx*4+3 -> dwords tx*2, tx*2+1
            *reinterpret_cast<uint2*>(
                &u_pk[(size_t)(row0 + ty * 4 + r) * 64 + tx * 2]) = o;
        }
        if (bid == 256 && tid < 64)
            w2_pk[tid] = pkh2(w2[2 * tid], w2[2 * tid + 1]);
    } else {
        const int bsel = row0 >> 12;
        #pragma unroll
        for (int r = 0; r < 4; ++r) {
            const int lrow = (row0 & 4095) + ty * 4 + r;
            uint2 o;
            o.x = pkh2(accx[r], accy[r]);
            o.y = pkh2(accz[r], accw[r]);
            *reinterpret_cast<uint2*>(
                &vh[((size_t)bsel * LL + lrow) * HH + tx * 4]) = o;
        }
    }
}

// ---------------------------------------------------------------------------
// K2: scores. 256 blocks x 512 threads (1 block/CU, 2 waves/SIMD).
// Block m = cb + 8*(kt + 16*b): reader XCD cb == writer XCD for that chunk.
// Thread owns ONE l-row (contiguous fp16, 16 b128 loads w/ immediate offsets)
// x 8 k-rows (register reuse). u_pk/w2_pk reads are wave-uniform -> s_load
// (scalar pipe; <=1 SGPR operand per pk instruction). No LDS at all.
// fp16 h-pair accumulation, chain 8, f32 flush per 16 h.
// ---------------------------------------------------------------------------
__global__ __launch_bounds__(512) void k2_score(
    const uint32_t* __restrict__ u_pk, const uint32_t* __restrict__ w2_pk,
    const __half* __restrict__ vh, float* __restrict__ out)
{
    int m = blockIdx.x;
    const int cb = m & 7;   m >>= 3;
    const int kt = m & 15;  m >>= 4;
    const int b  = m;
    const int tid = threadIdx.x;

    const int l = cb * 512 + tid;
    const uint4* vrow = reinterpret_cast<const uint4*>(
                            vh + ((size_t)b * LL + l) * HH);
    const uint32_t* up = u_pk + (size_t)(b * KK + kt * 8) * 64;  // uniform
    const __half2 hz = __float2half2_rn(0.f);

    float acc[8];
    #pragma unroll
    for (int k = 0; k < 8; ++k) acc[k] = 0.f;

    #pragma unroll
    for (int g = 0; g < 8; ++g) {          // 16 h per group
        const uint4 va = vrow[2 * g];
        const uint4 vb = vrow[2 * g + 1];
        uint32_t v[8];
        v[0] = va.x; v[1] = va.y; v[2] = va.z; v[3] = va.w;
        v[4] = vb.x; v[5] = vb.y; v[6] = vb.z; v[7] = vb.w;

        __half2 h2[8];
        #pragma unroll
        for (int k = 0; k < 8; ++k) h2[k] = hz;

        #pragma unroll
        for (int k = 0; k < 8; ++k) {
            #pragma unroll
            for (int j = 0; j < 8; ++j) {
                const __half2 uu = __builtin_bit_cast(__half2, up[k * 64 + g * 8 + j]);
                const __half2 ww = __builtin_bit_cast(__half2, w2_pk[g * 8 + j]);
                __half2 t = __hadd2(__builtin_bit_cast(__half2, v[j]), uu);
                h2[k] = __hfma2(hmax2(t, hz), ww, h2[k]);
            }
        }
        #pragma unroll
        for (int k = 0; k < 8; ++k) {
            const float2 f = __half22float2(h2[k]);
            acc[k] += f.x + f.y;
        }
    }

    #pragma unroll
    for (int k = 0; k < 8; ++k)
        out[(size_t)(b * KK + kt * 8 + k) * LL + l] = acc[k];
}

// ---------------------------------------------------------------------------
// K3: in-place row softmax WITHOUT max subtraction (|s| <~ 2 by construction;
// f32 exp has huge headroom; exp(s)/sum == softmax exactly). 256 x 1024.
// ---------------------------------------------------------------------------
__global__ __launch_bounds__(1024) void k3_softmax(float* __restrict__ out)
{
    __shared__ float reds[16];

    const int row = blockIdx.x;
    float* p = out + (size_t)row * LL;
    const int tid = threadIdx.x;

    float4 x = reinterpret_cast<const float4*>(p)[tid];

    x.x = expf(x.x); x.y = expf(x.y);
    x.z = expf(x.z); x.w = expf(x.w);
    float s = (x.x + x.y) + (x.z + x.w);
    #pragma unroll
    for (int off = 32; off > 0; off >>= 1)
        s += __shfl_xor(s, off, 64);
    const int lane = tid & 63, wv = tid >> 6;
    if (lane == 0) reds[wv] = s;
    __syncthreads();
    if (tid < 16) {
        float ss = reds[tid];
        #pragma unroll
        for (int off = 8; off > 0; off >>= 1)
            ss += __shfl_xor(ss, off, 64);
        reds[tid] = ss;
    }
    __syncthreads();
    s = reds[0];

    const float inv = 1.0f / s;
    x.x *= inv; x.y *= inv; x.z *= inv; x.w *= inv;
    reinterpret_cast<float4*>(p)[tid] = x;
}

// ---------------------------------------------------------------------------
extern "C" void kernel_launch(void* const* d_in, const int* in_sizes, int n_in,
                              void* d_out, int out_size, void* d_ws, size_t ws_size,
                              hipStream_t stream)
{
    const float* inA = (const float*)d_in[0];
    const float* inB = (const float*)d_in[1];
    const float* W1  = (const float*)d_in[2];
    const float* b1  = (const float*)d_in[3];
    const float* w2  = (const float*)d_in[4];
    float* out = (float*)d_out;

    char* ws = (char*)d_ws;
    uint32_t* u_pk  = (uint32_t*)ws;                      // 64 KiB
    uint32_t* w2_pk = (uint32_t*)(ws + 0x10000);          // 256 B
    __half*   vh    = (__half*)(ws + 0x20000);            // 2 MiB

    hipLaunchKernelGGL(k1_gemm, dim3(264), dim3(256), 0, stream,
                       inA, inB, W1, b1, w2, u_pk, w2_pk, vh);
    hipLaunchKernelGGL(k2_score, dim3(256), dim3(512), 0, stream,
                       u_pk, w2_pk, vh, out);
    hipLaunchKernelGGL(k3_softmax, dim3(BB * KK), dim3(1024), 0, stream, out);
}

// Round 15
// 28.397 us; speedup vs baseline: 10.1795x; 1.1056x over previous
//
#include <hip/hip_runtime.h>
#include <hip/hip_fp16.h>
#include <math.h>

// Problem constants: B=2, K=128, L=4096, DK=DL=128, HID=128
constexpr int BB = 2;
constexpr int KK = 128;
constexpr int LL = 4096;
constexpr int DD = 128;
constexpr int HH = 128;

typedef _Float16 f16x2 __attribute__((ext_vector_type(2)));

__device__ __forceinline__ float4 ld4(const float* p) {
    return *reinterpret_cast<const float4*>(p);
}

// pack two floats into a half2 dword
__device__ __forceinline__ uint32_t pkh2(float a, float b) {
    return __builtin_bit_cast(uint32_t, __floats2half2_rn(a, b));
}

// duplicate fp16(x) into both halves of a dword
__device__ __forceinline__ uint32_t duph(float x) {
    __half h = __float2half(x);
    unsigned short us = __builtin_bit_cast(unsigned short, h);
    return (uint32_t)us * 0x10001u;
}

// ---------------------------------------------------------------------------
// vT2 layout: dword(b, g, lp, ph) = ((b*8 + g)*2048 + lp)*16 + ph
//   g = h/16 (8 groups), ph = h%16, lp = l/2; dword = half2(v[2lp][h], v[2lp+1][h])
// A thread's 16-h group at fixed lp is 64 B CONTIGUOUS -> 4 b128 loads.
// ---------------------------------------------------------------------------

// ---------------------------------------------------------------------------
// K1: 264 blocks x 256 threads, 32 virtual rows. W1-half staged into LDS in
// two 32 KB chunks (R10-proven). B-rows stored DIRECTLY from registers into
// vT2 (no LDS transpose); A-rows -> u_dup (dup'd fp16); block 256 -> w2_dup.
// B-tiles XCD-swizzled: writer XCD = (l-chunk)&7 = k2 reader XCD.
// ---------------------------------------------------------------------------
__global__ __launch_bounds__(256) void k1_gemm(
    const float* __restrict__ inA, const float* __restrict__ inB,
    const float* __restrict__ W1, const float* __restrict__ b1,
    const float* __restrict__ w2,
    uint32_t* __restrict__ u_dup, uint32_t* __restrict__ w2_dup,
    uint32_t* __restrict__ vT2)
{
    __shared__ __align__(16) char smem[48 * 1024];
    float*  sIn = reinterpret_cast<float*>(smem);               // 16 KiB
    float4* sW4 = reinterpret_cast<float4*>(smem + 16 * 1024);  // 32 KiB

    const int bid = blockIdx.x;
    const int tid = threadIdx.x;

    int row0;
    bool isA;
    if (bid < 256) {
        const int x = bid & 7, y = bid >> 3;
        const int C = x + 8 * (y & 1);
        row0 = C * 512 + (y >> 1) * 32;    // B virtual row (b*4096 + l)
        isA = false;
    } else {
        row0 = (bid - 256) * 32;           // u row
        isA = true;
    }
    const float* src = (isA ? inA : inB) + (size_t)row0 * DD;
    const float4* wsrc = reinterpret_cast<const float4*>(W1 + (isA ? 0 : DD * HH));

    #pragma unroll
    for (int j = 0; j < 4; ++j) {
        const int idx = tid + 256 * j;
        reinterpret_cast<float4*>(sIn)[idx] =
            reinterpret_cast<const float4*>(src)[idx];
    }

    const int tx = tid & 31;   // h-cols tx*4 .. tx*4+3
    const int ty = tid >> 5;   // rows ty*4 .. ty*4+3

    float acc[4][4];           // [row r][h-col c]
    #pragma unroll
    for (int r = 0; r < 4; ++r)
        #pragma unroll
        for (int c = 0; c < 4; ++c) acc[r][c] = 0.f;

    for (int wh = 0; wh < 2; ++wh) {
        __syncthreads();
        #pragma unroll
        for (int q = 0; q < 8; ++q)
            sW4[tid + 256 * q] = wsrc[wh * 2048 + tid + 256 * q];
        __syncthreads();

        #pragma unroll 2
        for (int dd0 = 0; dd0 < 64; dd0 += 4) {
            const int d0 = wh * 64 + dd0;
            float4 w4[4];
            #pragma unroll
            for (int dd = 0; dd < 4; ++dd)
                w4[dd] = sW4[(dd0 + dd) * 32 + tx];
            float a[4][4];
            #pragma unroll
            for (int r = 0; r < 4; ++r) {
                float4 a4 = ld4(&sIn[(ty * 4 + r) * 128 + d0]);
                a[r][0] = a4.x; a[r][1] = a4.y; a[r][2] = a4.z; a[r][3] = a4.w;
            }
            #pragma unroll
            for (int dd = 0; dd < 4; ++dd) {
                const float4 wv = w4[dd];
                #pragma unroll
                for (int r = 0; r < 4; ++r) {
                    const float av = a[r][dd];
                    acc[r][0] = fmaf(av, wv.x, acc[r][0]);
                    acc[r][1] = fmaf(av, wv.y, acc[r][1]);
                    acc[r][2] = fmaf(av, wv.z, acc[r][2]);
                    acc[r][3] = fmaf(av, wv.w, acc[r][3]);
                }
            }
        }
    }

    if (isA) {
        const float4 bb = ld4(&b1[tx * 4]);
        const float bv[4] = { bb.x, bb.y, bb.z, bb.w };
        #pragma unroll
        for (int r = 0; r < 4; ++r) {
            uint4 o;
            o.x = duph(acc[r][0] + bv[0]);
            o.y = duph(acc[r][1] + bv[1]);
            o.z = duph(acc[r][2] + bv[2]);
            o.w = duph(acc[r][3] + bv[3]);
            *reinterpret_cast<uint4*>(
                &u_dup[(size_t)(row0 + ty * 4 + r) * HH + tx * 4]) = o;
        }
        if (bid == 256 && tid < HH) w2_dup[tid] = duph(w2[tid]);
    } else {
        // direct register -> vT2 stores (8 dwords; lines fully written per wave)
        const int bsel = row0 >> 12;
        const int lp0  = ((row0 & 4095) + ty * 4) >> 1;   // 2 lp: lp0, lp0+1
        uint32_t* vb = vT2 + (size_t)bsel * (8 * 2048 * 16);
        #pragma unroll
        for (int c = 0; c < 4; ++c) {
            const int h = tx * 4 + c, g = h >> 4, ph = h & 15;
            uint32_t* dst = vb + ((size_t)g * 2048 + lp0) * 16 + ph;
            dst[0]  = pkh2(acc[0][c], acc[1][c]);   // lp0   : (l, l+1)
            dst[16] = pkh2(acc[2][c], acc[3][c]);   // lp0+1 : (l+2, l+3)
        }
    }
}

// ---------------------------------------------------------------------------
// K2: scores. 256 blocks x 512 threads (1 block/CU). Block m = cb + 8*(kt+16*b):
// reader XCD cb == writer XCD. kh=tid>>8 picks 4 k; t=tid&255 picks lp.
// Per 16-h group: 4 contiguous b128 v-loads, u/w2 from LDS (uniform broadcast
// b128), native f16x2 math (pk_add / pk_max / pk_fma), f32 flush per group.
// ---------------------------------------------------------------------------
__global__ __launch_bounds__(512) void k2_score(
    const uint32_t* __restrict__ u_dup, const uint32_t* __restrict__ w2_dup,
    const uint32_t* __restrict__ vT2, float* __restrict__ out)
{
    __shared__ __align__(16) uint32_t sU[8 * HH];   // 4 KiB
    __shared__ __align__(16) uint32_t sW[HH];       // 512 B

    int m = blockIdx.x;
    const int cb = m & 7;   m >>= 3;
    const int kt = m & 15;  m >>= 4;
    const int b  = m;
    const int tid = threadIdx.x;

    if (tid < 256)
        reinterpret_cast<uint4*>(sU)[tid] =
            reinterpret_cast<const uint4*>(u_dup + (size_t)(b * KK + kt * 8) * HH)[tid];
    else if (tid < 288)
        reinterpret_cast<uint4*>(sW)[tid - 256] =
            reinterpret_cast<const uint4*>(w2_dup)[tid - 256];
    __syncthreads();

    const int kh = tid >> 8;        // k rows kt*8 + kh*4 .. +3
    const int t  = tid & 255;
    const int lp = cb * 256 + t;    // l-pair within b

    const uint4* vg = reinterpret_cast<const uint4*>(
                          vT2 + ((size_t)b * 8 * 2048 + lp) * 16);
    const uint4* su4 = reinterpret_cast<const uint4*>(sU + kh * 4 * HH);
    const uint4* sw4 = reinterpret_cast<const uint4*>(sW);

    const f16x2 hz = { (_Float16)0, (_Float16)0 };
    float2 facc[4];
    #pragma unroll
    for (int k = 0; k < 4; ++k) { facc[k].x = 0.f; facc[k].y = 0.f; }

    #pragma unroll
    for (int g = 0; g < 8; ++g) {          // 16 h per group, 64 B contiguous
        uint4 vq[4];
        #pragma unroll
        for (int c = 0; c < 4; ++c)
            vq[c] = vg[(size_t)g * 8192 + c];      // 8192 uint4 = 2048 lp * 64 B
        const uint32_t* vd = reinterpret_cast<const uint32_t*>(vq);

        uint4 wq[4];
        #pragma unroll
        for (int c = 0; c < 4; ++c) wq[c] = sw4[g * 4 + c];
        const uint32_t* wd = reinterpret_cast<const uint32_t*>(wq);

        f16x2 hacc[4] = { hz, hz, hz, hz };
        #pragma unroll
        for (int k = 0; k < 4; ++k) {
            uint4 uq[4];
            #pragma unroll
            for (int c = 0; c < 4; ++c) uq[c] = su4[k * 32 + g * 4 + c];
            const uint32_t* ud = reinterpret_cast<const uint32_t*>(uq);
            #pragma unroll
            for (int ph = 0; ph < 16; ++ph) {
                f16x2 vv = __builtin_bit_cast(f16x2, vd[ph]);
                f16x2 uu = __builtin_bit_cast(f16x2, ud[ph]);
                f16x2 ww = __builtin_bit_cast(f16x2, wd[ph]);
                f16x2 s = vv + uu;                          // v_pk_add_f16
                s = __builtin_elementwise_max(s, hz);       // v_pk_max_f16
                hacc[k] = s * ww + hacc[k];                 // v_pk_fma_f16
            }
        }
        #pragma unroll
        for (int k = 0; k < 4; ++k) {
            facc[k].x += (float)hacc[k].x;
            facc[k].y += (float)hacc[k].y;
        }
    }

    #pragma unroll
    for (int k = 0; k < 4; ++k)
        *reinterpret_cast<float2*>(
            &out[(size_t)(b * KK + kt * 8 + kh * 4 + k) * LL + 2 * lp]) = facc[k];
}

// ---------------------------------------------------------------------------
// K3: in-place row softmax WITHOUT max subtraction (|s| <~ 2; f32 exp has huge
// headroom; exp(s)/sum == softmax exactly). 256 blocks x 1024 threads.
// ---------------------------------------------------------------------------
__global__ __launch_bounds__(1024) void k3_softmax(float* __restrict__ out)
{
    __shared__ float reds[16];

    const int row = blockIdx.x;
    float* p = out + (size_t)row * LL;
    const int tid = threadIdx.x;

    float4 x = reinterpret_cast<const float4*>(p)[tid];

    x.x = expf(x.x); x.y = expf(x.y);
    x.z = expf(x.z); x.w = expf(x.w);
    float s = (x.x + x.y) + (x.z + x.w);
    #pragma unroll
    for (int off = 32; off > 0; off >>= 1)
        s += __shfl_xor(s, off, 64);
    const int lane = tid & 63, wv = tid >> 6;
    if (lane == 0) reds[wv] = s;
    __syncthreads();
    if (tid < 16) {
        float ss = reds[tid];
        #pragma unroll
        for (int off = 8; off > 0; off >>= 1)
            ss += __shfl_xor(ss, off, 64);
        reds[tid] = ss;
    }
    __syncthreads();
    s = reds[0];

    const float inv = 1.0f / s;
    x.x *= inv; x.y *= inv; x.z *= inv; x.w *= inv;
    reinterpret_cast<float4*>(p)[tid] = x;
}

// ---------------------------------------------------------------------------
extern "C" void kernel_launch(void* const* d_in, const int* in_sizes, int n_in,
                              void* d_out, int out_size, void* d_ws, size_t ws_size,
                              hipStream_t stream)
{
    const float* inA = (const float*)d_in[0];
    const float* inB = (const float*)d_in[1];
    const float* W1  = (const float*)d_in[2];
    const float* b1  = (const float*)d_in[3];
    const float* w2  = (const float*)d_in[4];
    float* out = (float*)d_out;

    char* ws = (char*)d_ws;
    uint32_t* u_dup  = (uint32_t*)ws;                      // 128 KiB
    uint32_t* w2_dup = (uint32_t*)(ws + 0x20000);          // 512 B
    uint32_t* vT2    = (uint32_t*)(ws + 0x40000);          // 2 MiB

    hipLaunchKernelGGL(k1_gemm, dim3(264), dim3(256), 0, stream,
                       inA, inB, W1, b1, w2, u_dup, w2_dup, vT2);
    hipLaunchKernelGGL(k2_score, dim3(256), dim3(512), 0, stream,
                       u_dup, w2_dup, vT2, out);
    hipLaunchKernelGGL(k3_softmax, dim3(BB * KK), dim3(1024), 0, stream, out);
}